// Round 4
// baseline (2740.695 us; speedup 1.0000x reference)
//
#include <hip/hip_runtime.h>
#include <hip/hip_bf16.h>
#include <math.h>

#define BB 8
#define EE 768
#define HH 12
#define LL 12
#define DD 64
#define MLPD 3072
#define NN 197
#define NPATCH 196
#define NCLS 1000
#define NROWS (BB*NN)        // 1576
#define PROWS (BB*NPATCH)    // 1568
#define MPAD 1664            // 13 * 128
#define HTILES 13            // MPAD/128
#define NBH (BB*HH)          // 96
#define NP224 224
#define NP256 256
#define SCALE 0.125f

#define MODE_F32   0
#define MODE_ELU1F 1
#define MODE_GELUB 2
#define MODE_RESF  3

typedef __attribute__((ext_vector_type(8))) short bf16x8;
typedef __attribute__((ext_vector_type(4))) float f32x4;

__device__ __forceinline__ unsigned short f2b(float f) {
    union { __hip_bfloat16 h; unsigned short u; } x;
    x.h = __float2bfloat16(f);
    return x.u;
}

__device__ __forceinline__ float b2f(unsigned short u) {
    union { unsigned int i; float f; } x;
    x.i = ((unsigned int)u) << 16;
    return x.f;
}

#define GLD(gptr, lptr) __builtin_amdgcn_global_load_lds( \
    (const __attribute__((address_space(1))) unsigned int*)(gptr), \
    (__attribute__((address_space(3))) unsigned int*)(lptr), 16, 0, 0)

// =============== dual-half MFMA bf16 GEMM (2-phase double-buffered) ===============
// blockIdx.y in [0,26): half = y>=13 selects {A,W,bias,mode,resid,out} set.
__global__ __launch_bounds__(256) void mfma_gemm2(
    const unsigned short* __restrict__ A0, const unsigned short* __restrict__ A1,
    const unsigned short* __restrict__ W0, const unsigned short* __restrict__ W1,
    const float* __restrict__ bias0, const float* __restrict__ bias1,
    int K, int Nc, int mode0, int mode1,
    const float* __restrict__ gamma,
    const float* __restrict__ resid0, const float* __restrict__ resid1,
    float* __restrict__ Cf0, float* __restrict__ Cf1,
    unsigned short* __restrict__ Cb0, unsigned short* __restrict__ Cb1)
{
    __shared__ unsigned short lA[2][128 * 32];
    __shared__ unsigned short lB[2][128 * 32];
    const int tid  = threadIdx.x;
    const int lane = tid & 63;
    const int wave = tid >> 6;
    const int wm = wave >> 1, wn = wave & 1;
    const int half = blockIdx.y >= HTILES;
    const int mout0 = (blockIdx.y - (half ? HTILES : 0)) * 128;
    const int n0 = blockIdx.x * 128;
    const unsigned short* A = half ? A1 : A0;
    const unsigned short* W = half ? W1 : W0;
    const float* bias = half ? bias1 : bias0;
    const float* resid = half ? resid1 : resid0;
    float* Cf = half ? Cf1 : Cf0;
    unsigned short* Cb = half ? Cb1 : Cb0;
    const int mode = half ? mode1 : mode0;

    const int srow  = lane >> 2;
    const int skoff = (lane & 3) * 8;
    const int fr = lane & 15;
    const int fk = (lane >> 4) * 8;

    auto stage = [&](int bufi, int k0) {
#pragma unroll
        for (int i = 0; i < 2; i++) {
            int chunk = wave * 2 + i;
            int row = chunk * 16 + srow;
            GLD(A + (size_t)(mout0 + row) * K + k0 + skoff, &lA[bufi][chunk * 512]);
            GLD(W + (size_t)(n0 + row) * K + k0 + skoff, &lB[bufi][chunk * 512]);
        }
    };

    f32x4 acc[4][4];
#pragma unroll
    for (int i = 0; i < 4; i++)
#pragma unroll
        for (int j = 0; j < 4; j++) acc[i][j] = (f32x4){0.f, 0.f, 0.f, 0.f};

    const int NT = K >> 5;
    stage(0, 0);
    __syncthreads();
    int cur = 0;
    for (int t = 0; t < NT; t++) {
        if (t + 1 < NT) stage(cur ^ 1, (t + 1) * 32);
        bf16x8 a[4], b[4];
#pragma unroll
        for (int q = 0; q < 4; q++) {
            a[q] = *(const bf16x8*)(&lA[cur][(wm * 64 + q * 16 + fr) * 32 + fk]);
            b[q] = *(const bf16x8*)(&lB[cur][(wn * 64 + q * 16 + fr) * 32 + fk]);
        }
#pragma unroll
        for (int i = 0; i < 4; i++)
#pragma unroll
            for (int j = 0; j < 4; j++)
                acc[i][j] = __builtin_amdgcn_mfma_f32_16x16x32_bf16(a[i], b[j], acc[i][j], 0, 0, 0);
        __syncthreads();
        cur ^= 1;
    }

    const int crow0 = mout0 + wm * 64;
    const int ccol0 = n0 + wn * 64;
    const int lr = (lane >> 4) * 4;
    const int lc = lane & 15;
#pragma unroll
    for (int i = 0; i < 4; i++) {
#pragma unroll
        for (int j = 0; j < 4; j++) {
            int col = ccol0 + j * 16 + lc;
            float bv = bias ? bias[col] : 0.f;
#pragma unroll
            for (int r = 0; r < 4; r++) {
                int row = crow0 + i * 16 + lr + r;
                float v = acc[i][j][r] + bv;
                size_t o = (size_t)row * Nc + col;
                if (mode == MODE_ELU1F) {
                    Cf[o] = (v > 0.f) ? (v + 1.f) : expf(v);
                } else if (mode == MODE_GELUB) {
                    v = 0.5f * v * (1.f + erff(v * 0.70710678118654752f));
                    Cb[o] = f2b(v);
                } else if (mode == MODE_RESF) {
                    Cf[o] = resid[o] + gamma[col] * v;
                } else {
                    Cf[o] = v;
                }
            }
        }
    }
}

// =============== split-K dual-half MFMA GEMM (2-phase dbuf): fp32 partials ===============
// grid (Nc/128, 2*HTILES, S). Partial layout: P[(half*S + z)][MPAD][Nc].
__global__ __launch_bounds__(256) void mfma_gemm2_sk(
    const unsigned short* __restrict__ A0, const unsigned short* __restrict__ A1,
    const unsigned short* __restrict__ W0, const unsigned short* __restrict__ W1,
    int K, int Kc, int Nc, int S,
    float* __restrict__ P)
{
    __shared__ unsigned short lA[2][128 * 32];
    __shared__ unsigned short lB[2][128 * 32];
    const int tid  = threadIdx.x;
    const int lane = tid & 63;
    const int wave = tid >> 6;
    const int wm = wave >> 1, wn = wave & 1;
    const int half = blockIdx.y >= HTILES;
    const int mout0 = (blockIdx.y - (half ? HTILES : 0)) * 128;
    const int n0 = blockIdx.x * 128;
    const int z = blockIdx.z;
    const int kb = z * Kc;
    const unsigned short* A = half ? A1 : A0;
    const unsigned short* W = half ? W1 : W0;

    const int srow  = lane >> 2;
    const int skoff = (lane & 3) * 8;
    const int fr = lane & 15;
    const int fk = (lane >> 4) * 8;

    auto stage = [&](int bufi, int k0) {
#pragma unroll
        for (int i = 0; i < 2; i++) {
            int chunk = wave * 2 + i;
            int row = chunk * 16 + srow;
            GLD(A + (size_t)(mout0 + row) * K + k0 + skoff, &lA[bufi][chunk * 512]);
            GLD(W + (size_t)(n0 + row) * K + k0 + skoff, &lB[bufi][chunk * 512]);
        }
    };

    f32x4 acc[4][4];
#pragma unroll
    for (int i = 0; i < 4; i++)
#pragma unroll
        for (int j = 0; j < 4; j++) acc[i][j] = (f32x4){0.f, 0.f, 0.f, 0.f};

    const int NT = Kc >> 5;
    stage(0, kb);
    __syncthreads();
    int cur = 0;
    for (int t = 0; t < NT; t++) {
        if (t + 1 < NT) stage(cur ^ 1, kb + (t + 1) * 32);
        bf16x8 a[4], b[4];
#pragma unroll
        for (int q = 0; q < 4; q++) {
            a[q] = *(const bf16x8*)(&lA[cur][(wm * 64 + q * 16 + fr) * 32 + fk]);
            b[q] = *(const bf16x8*)(&lB[cur][(wn * 64 + q * 16 + fr) * 32 + fk]);
        }
#pragma unroll
        for (int i = 0; i < 4; i++)
#pragma unroll
            for (int j = 0; j < 4; j++)
                acc[i][j] = __builtin_amdgcn_mfma_f32_16x16x32_bf16(a[i], b[j], acc[i][j], 0, 0, 0);
        __syncthreads();
        cur ^= 1;
    }

    float* Pout = P + (size_t)(half * S + z) * MPAD * Nc;
    const int crow0 = mout0 + wm * 64;
    const int ccol0 = n0 + wn * 64;
    const int lr = (lane >> 4) * 4;
    const int lc = lane & 15;
#pragma unroll
    for (int i = 0; i < 4; i++) {
#pragma unroll
        for (int j = 0; j < 4; j++) {
            int col = ccol0 + j * 16 + lc;
#pragma unroll
            for (int r = 0; r < 4; r++) {
                int row = crow0 + i * 16 + lr + r;
                Pout[(size_t)row * Nc + col] = acc[i][j][r];
            }
        }
    }
}

// =============== split-K reduce (elementwise, patch embed only) ===============
__global__ __launch_bounds__(256) void sk_reduce_kernel(
    const float* __restrict__ P, int S, int Nc,
    const float* __restrict__ bias0, const float* __restrict__ bias1,
    float* __restrict__ C0, float* __restrict__ C1)
{
    const size_t per = (size_t)MPAD * Nc;
    size_t gi = ((size_t)blockIdx.x * 256 + threadIdx.x) * 4;
    if (gi >= per) return;
    const int half = blockIdx.y;
    const float* p = P + (size_t)half * S * per + gi;
    float4 s = *(const float4*)p;
    for (int z = 1; z < S; z++) {
        float4 q = *(const float4*)(p + (size_t)z * per);
        s.x += q.x; s.y += q.y; s.z += q.z; s.w += q.w;
    }
    const int col = (int)(gi % (size_t)Nc);
    const float* bias = half ? bias1 : bias0;
    float4 bv = *(const float4*)(bias + col);
    s.x += bv.x; s.y += bv.y; s.z += bv.z; s.w += bv.w;
    float* C = half ? C1 : C0;
    *(float4*)(C + gi) = s;
}

// =============== split-K reduce + residual + fused LayerNorm ===============
// grid (MPAD, 2), 256 threads. One row per block:
//   C = resid + gamma * (sum_z P[z] + bias)   (fp32, residual stream)
//   Y = LN(C) * lnG + lnB                      (bf16, next GEMM input; skip if !Y)
__global__ __launch_bounds__(256) void sk_reduce_ln(
    const float* __restrict__ P, int S,
    const float* __restrict__ bias0, const float* __restrict__ bias1,
    const float* __restrict__ gamma,
    const float* __restrict__ resid0, const float* __restrict__ resid1,
    float* __restrict__ C0, float* __restrict__ C1,
    const float* __restrict__ lnG, const float* __restrict__ lnB,
    unsigned short* __restrict__ Y)
{
    const int row = blockIdx.x;
    const int half = blockIdx.y;
    const int tid = threadIdx.x;
    const size_t per = (size_t)MPAD * EE;
    const float* p = P + (size_t)half * S * per + (size_t)row * EE;
    const float* bias = half ? bias1 : bias0;
    const float* resid = half ? resid1 : resid0;
    float* C = half ? C1 : C0;
    float v[3];
#pragma unroll
    for (int i = 0; i < 3; i++) {
        int e = tid + i * 256;
        float s = p[e];
        for (int z = 1; z < S; z++) s += p[(size_t)z * per + e];
        v[i] = resid[(size_t)row * EE + e] + gamma[e] * (s + bias[e]);
        C[(size_t)row * EE + e] = v[i];
    }
    if (!Y) return;
    __shared__ float red[256];
    red[tid] = v[0] + v[1] + v[2];
    __syncthreads();
    for (int s2 = 128; s2 > 0; s2 >>= 1) { if (tid < s2) red[tid] += red[tid + s2]; __syncthreads(); }
    float mu = red[0] * (1.f / 768.f);
    __syncthreads();
    float d0 = v[0] - mu, d1 = v[1] - mu, d2 = v[2] - mu;
    red[tid] = d0 * d0 + d1 * d1 + d2 * d2;
    __syncthreads();
    for (int s2 = 128; s2 > 0; s2 >>= 1) { if (tid < s2) red[tid] += red[tid + s2]; __syncthreads(); }
    float rstd = rsqrtf(red[0] * (1.f / 768.f) + 1e-5f);
    unsigned short* yr = Y + ((size_t)half * MPAD + row) * EE;
    yr[tid]       = f2b(d0 * rstd * lnG[tid]       + lnB[tid]);
    yr[tid + 256] = f2b(d1 * rstd * lnG[tid + 256] + lnB[tid + 256]);
    yr[tid + 512] = f2b(d2 * rstd * lnG[tid + 512] + lnB[tid + 512]);
}

// =============== attention pre: operands + coalesced transpose ===============
__global__ __launch_bounds__(256) void pre_kernel(
    const float* __restrict__ qkv, const float* __restrict__ cqkv,
    unsigned short* __restrict__ Aq, unsigned short* __restrict__ Bk,
    float* __restrict__ rsum, float* __restrict__ csum,
    unsigned short* __restrict__ vT, unsigned short* __restrict__ cvT)
{
    const int t = blockIdx.x;
    const int bh = blockIdx.y;
    const int b = bh / HH, h = bh % HH;
    const int n0 = t * 64;
    const int lane = threadIdx.x & 63;
    const int w = threadIdx.x >> 6;
    __shared__ unsigned short vs[64][66];
    __shared__ unsigned short cvs[64][66];

    for (int p = 0; p < 16; p++) {
        int nl = p * 4 + w;
        int n = n0 + nl;
        int d = lane;
        size_t arow = ((size_t)bh * NP256 + n) * 128;
        if (n < NN) {
            size_t basei = (size_t)(b * NN + n) * 3 * EE + h * DD + d;
            float q  = qkv[basei];
            float k  = qkv[basei + EE];
            float v  = qkv[basei + 2 * EE];
            float cq = cqkv[basei];
            float ck = cqkv[basei + EE];
            float cv = cqkv[basei + 2 * EE];
            float qs = q * SCALE;
            float sqq = sqrtf(fmaxf(cq, 1e-24f));
            float sqk = sqrtf(fmaxf(ck, 1e-24f));
            Aq[arow + d]      = f2b(qs);
            Aq[arow + 64 + d] = f2b(sqq);
            Bk[arow + d]      = f2b(k);
            Bk[arow + 64 + d] = f2b(sqk);
            vs[nl][d]  = f2b(v);
            cvs[nl][d] = f2b(cv);
            float r = qs * qs + cq;
            float c = k * k + ck;
            for (int off2 = 32; off2 > 0; off2 >>= 1) {
                r += __shfl_down(r, off2);
                c += __shfl_down(c, off2);
            }
            if (d == 0) { rsum[bh * NP256 + n] = r; csum[bh * NP256 + n] = c; }
        } else {
            ((unsigned int*)(Aq + arow))[d] = 0u;
            ((unsigned int*)(Bk + arow))[d] = 0u;
            vs[nl][d] = 0; cvs[nl][d] = 0;
            if (d == 0) { rsum[bh * NP256 + n] = 0.f; csum[bh * NP256 + n] = 0.f; }
        }
    }
    __syncthreads();
    for (int p = 0; p < 16; p++) {
        int dr = p * 4 + w;
        int n = n0 + lane;
        if (n < NP224) {
            vT [((size_t)bh * 64 + dr) * NP224 + n] = vs[lane][dr];
            cvT[((size_t)bh * 64 + dr) * NP224 + n] = cvs[lane][dr];
        }
    }
}

// =============== fused attention: wasserstein + sigmoid + rpb + softmax + PV ===============
#define PADW 232   // 464 B rows: 16B-aligned, bank-spread
__global__ __launch_bounds__(256) void attn_fused(
    const unsigned short* __restrict__ Aq, const unsigned short* __restrict__ Bk,
    const float* __restrict__ rsum, const float* __restrict__ csum,
    const float* __restrict__ rpb,
    const unsigned short* __restrict__ vT, const unsigned short* __restrict__ cvT,
    unsigned short* __restrict__ ctxm, unsigned short* __restrict__ ctxc)
{
    __shared__ unsigned short lA[64 * 32];     // 4 KB
    __shared__ unsigned short lB[256 * 32];    // 16 KB
    __shared__ unsigned short lB2[128 * 32];   // 8 KB
    __shared__ unsigned short pL[64 * PADW];   // 29.7 KB
    const int tid = threadIdx.x, lane = tid & 63, w = tid >> 6;
    const int bh = blockIdx.y;
    const int b = bh / HH, h = bh % HH;
    const int q0 = blockIdx.x * 64;
    const int srow = lane >> 2, skoff = (lane & 3) * 8;
    const int fr = lane & 15, fk = (lane >> 4) * 8;
    const int lr4 = (lane >> 4) * 4;
    const unsigned short* A = Aq + (size_t)bh * NP256 * 128;
    const unsigned short* B = Bk + (size_t)bh * NP256 * 128;

    // ---- phase 1: S[64 x 256] = Aq @ Bk^T (K=128) ----
    f32x4 accS[16];
#pragma unroll
    for (int j = 0; j < 16; j++) accS[j] = (f32x4){0.f, 0.f, 0.f, 0.f};

    for (int k0 = 0; k0 < 128; k0 += 32) {
        GLD(A + (size_t)(q0 + w * 16 + srow) * 128 + k0 + skoff, lA + w * 512);
#pragma unroll
        for (int i = 0; i < 4; i++) {
            int chunk = w * 4 + i;
            GLD(B + (size_t)(chunk * 16 + srow) * 128 + k0 + skoff, lB + chunk * 512);
        }
        __syncthreads();
        bf16x8 a = *(const bf16x8*)(lA + (w * 16 + fr) * 32 + fk);
#pragma unroll
        for (int j = 0; j < 16; j++) {
            bf16x8 bb = *(const bf16x8*)(lB + (j * 16 + fr) * 32 + fk);
            accS[j] = __builtin_amdgcn_mfma_f32_16x16x32_bf16(a, bb, accS[j], 0, 0, 0);
        }
        __syncthreads();
    }

    // ---- epilogue + row softmax, fully in registers ----
    float rs[4];
#pragma unroll
    for (int r = 0; r < 4; r++) rs[r] = rsum[bh * NP256 + q0 + w * 16 + lr4 + r];
    float cs[16];
#pragma unroll
    for (int j = 0; j < 16; j++) cs[j] = csum[bh * NP256 + j * 16 + fr];

#pragma unroll
    for (int r = 0; r < 4; r++) {
        int rowg = q0 + w * 16 + lr4 + r;
        float v[16];
#pragma unroll
        for (int j = 0; j < 16; j++) {
            int col = j * 16 + fr;
            float z = 2.f * accS[j][r] - rs[r] - cs[j] + 1e-24f;
            float s = 1.f / (1.f + expf(-z));
            float rp = (col < NN && rowg < NN) ? rpb[((size_t)h * NN + rowg) * NN + col] : 0.f;
            v[j] = (col < NN) ? (s + rp) : -1e30f;
        }
        float mx = -1e30f;
#pragma unroll
        for (int j = 0; j < 16; j++) mx = fmaxf(mx, v[j]);
        mx = fmaxf(mx, __shfl_xor(mx, 1));
        mx = fmaxf(mx, __shfl_xor(mx, 2));
        mx = fmaxf(mx, __shfl_xor(mx, 4));
        mx = fmaxf(mx, __shfl_xor(mx, 8));
        float sum = 0.f;
#pragma unroll
        for (int j = 0; j < 16; j++) { v[j] = expf(v[j] - mx); sum += v[j]; }
        sum += __shfl_xor(sum, 1);
        sum += __shfl_xor(sum, 2);
        sum += __shfl_xor(sum, 4);
        sum += __shfl_xor(sum, 8);
        float inv = 1.f / sum;
        int rowl = w * 16 + lr4 + r;
#pragma unroll
        for (int j = 0; j < 14; j++)   // cols 224..255 are exactly 0, never read
            pL[rowl * PADW + j * 16 + fr] = f2b(v[j] * inv);
    }

    // ---- phase 2: ctx = P @ V^T and P^2 @ CV^T (K=224) ----
    f32x4 acc2[2][4];
#pragma unroll
    for (int p = 0; p < 2; p++)
#pragma unroll
        for (int j = 0; j < 4; j++) acc2[p][j] = (f32x4){0.f, 0.f, 0.f, 0.f};

    for (int k0 = 0; k0 < NP224; k0 += 32) {
#pragma unroll
        for (int i = 0; i < 2; i++) {
            int chunk = w * 2 + i;
            const unsigned short* src = (chunk < 4)
                ? (vT  + ((size_t)bh * 64 + chunk * 16 + srow) * NP224)
                : (cvT + ((size_t)bh * 64 + (chunk - 4) * 16 + srow) * NP224);
            GLD(src + k0 + skoff, lB2 + chunk * 512);
        }
        __syncthreads();   // also drains our own pL ds_writes on first iter
        bf16x8 ap = *(const bf16x8*)(pL + (w * 16 + fr) * PADW + k0 + fk);
        bf16x8 ap2;
#pragma unroll
        for (int e = 0; e < 8; e++) {
            float pv = b2f((unsigned short)ap[e]);
            ap2[e] = (short)f2b(pv * pv);
        }
#pragma unroll
        for (int j = 0; j < 4; j++) {
            bf16x8 bv = *(const bf16x8*)(lB2 + (j * 16 + fr) * 32 + fk);
            bf16x8 bc = *(const bf16x8*)(lB2 + ((64 + j * 16) + fr) * 32 + fk);
            acc2[0][j] = __builtin_amdgcn_mfma_f32_16x16x32_bf16(ap,  bv, acc2[0][j], 0, 0, 0);
            acc2[1][j] = __builtin_amdgcn_mfma_f32_16x16x32_bf16(ap2, bc, acc2[1][j], 0, 0, 0);
        }
        __syncthreads();
    }

#pragma unroll
    for (int j = 0; j < 4; j++) {
        int d = j * 16 + fr;
#pragma unroll
        for (int r = 0; r < 4; r++) {
            int n = q0 + w * 16 + lr4 + r;
            if (n >= NN) continue;
            size_t o = ((size_t)(b * NN + n)) * EE + h * DD + d;
            ctxm[o] = f2b(acc2[0][j][r]);
            ctxc[o] = f2b(acc2[1][j][r]);
        }
    }
}

// =============== head: wave-per-class dot product ===============
__global__ __launch_bounds__(256) void head_kernel(
    const float* __restrict__ pooled, const float* __restrict__ W,
    const float* __restrict__ bias, float* __restrict__ out)
{
    const int wv = threadIdx.x >> 6, lane = threadIdx.x & 63;
    const int c = blockIdx.x * 4 + wv;
    const int b = blockIdx.y;
    if (c >= NCLS) return;
    const float* wr = W + (size_t)c * EE;
    const float* pr = pooled + (size_t)b * EE;
    float s = 0.f;
#pragma unroll
    for (int i = 0; i < 12; i++) s += pr[lane + i * 64] * wr[lane + i * 64];
    for (int off = 32; off > 0; off >>= 1) s += __shfl_down(s, off);
    if (lane == 0) out[(size_t)b * NCLS + c] = s + bias[c];
}

#define W_QKV   0
#define W_PROJ  1769472
#define W_CPROJ 2359296
#define W_FC1   2949120
#define W_FC2   5308416
#define W_TOTAL 7667712
#define PW_ELEMS 589824

// =============== one-shot weight conversion: ALL layers + patch weights ===============
// 8 elems/thread, grid-stride. All region boundaries are multiples of 8.
__global__ __launch_bounds__(256) void cvt_all_kernel(
    const float* __restrict__ qkvw, const float* __restrict__ pw,
    const float* __restrict__ cpw, const float* __restrict__ f1,
    const float* __restrict__ f2,
    const float* __restrict__ patchw, const float* __restrict__ cpatchw,
    unsigned short* __restrict__ dst,
    unsigned short* __restrict__ dpw, unsigned short* __restrict__ dcpw)
{
    const size_t NW  = (size_t)LL * W_TOTAL;
    const size_t TOT = NW + 2 * (size_t)PW_ELEMS;
    const size_t stride = (size_t)gridDim.x * 256 * 8;
    for (size_t i = ((size_t)blockIdx.x * 256 + threadIdx.x) * 8; i < TOT; i += stride) {
        const float* s;
        unsigned short* d;
        if (i < NW) {
            int l = (int)(i / W_TOTAL);
            int r = (int)(i % W_TOTAL);
            if (r < W_PROJ)        s = qkvw + (size_t)l * (3 * EE * EE) + r;
            else if (r < W_CPROJ)  s = pw   + (size_t)l * (EE * EE)     + (r - W_PROJ);
            else if (r < W_FC1)    s = cpw  + (size_t)l * (EE * EE)     + (r - W_CPROJ);
            else if (r < W_FC2)    s = f1   + (size_t)l * (MLPD * EE)   + (r - W_FC1);
            else                   s = f2   + (size_t)l * (MLPD * EE)   + (r - W_FC2);
            d = dst + i;
        } else if (i < NW + PW_ELEMS) {
            size_t r = i - NW;
            s = patchw + r; d = dpw + r;
        } else {
            size_t r = i - NW - PW_ELEMS;
            s = cpatchw + r; d = dcpw + r;
        }
        float4 fa = *(const float4*)s;
        float4 fb = *(const float4*)(s + 4);
        union { ushort4 u4[2]; unsigned int w[4]; } o;
        o.u4[0].x = f2b(fa.x); o.u4[0].y = f2b(fa.y); o.u4[0].z = f2b(fa.z); o.u4[0].w = f2b(fa.w);
        o.u4[1].x = f2b(fb.x); o.u4[1].y = f2b(fb.y); o.u4[1].z = f2b(fb.z); o.u4[1].w = f2b(fb.w);
        *(uint4*)d = *(const uint4*)o.w;
    }
}

// =============== concat qkv biases: ALL layers ===============
// bqc layout: [LL][2][2304] fp32
__global__ __launch_bounds__(256) void qkvbias_all_kernel(
    const float* __restrict__ qb, const float* __restrict__ vb,
    const float* __restrict__ cqb, const float* __restrict__ cvb,
    float* __restrict__ bqc)
{
    int l = blockIdx.y;
    int j = blockIdx.x * 256 + threadIdx.x;
    if (j >= 3 * EE) return;
    float m, c;
    if (j < EE)        { m = qb[l * EE + j];          c = cqb[l * EE + j]; }
    else if (j < 2*EE) { m = 0.f;                      c = 0.f; }
    else               { m = vb[l * EE + j - 2 * EE];  c = cvb[l * EE + j - 2 * EE]; }
    bqc[(size_t)l * 4608 + j]        = m;
    bqc[(size_t)l * 4608 + 2304 + j] = c;
}

// =============== im2col (bf16 out) ===============
__global__ __launch_bounds__(256) void im2col_kernel(
    const float* __restrict__ x, unsigned short* __restrict__ col)
{
    int idx = blockIdx.x * 256 + threadIdx.x;
    if (idx >= PROWS * EE) return;
    int c = idx % EE;
    int r = idx / EE;
    int b = r / NPATCH;
    int p = r % NPATCH;
    int ph = p / 14, pw = p % 14;
    int ch = c >> 8;
    int rem = c & 255;
    int i = rem >> 4, j = rem & 15;
    col[idx] = f2b(x[(((size_t)b * 3 + ch) * 224 + (ph * 16 + i)) * 224 + (pw * 16 + j)]);
}

// =============== assemble tokens ===============
__global__ __launch_bounds__(256) void assemble_kernel(
    const float* __restrict__ tm, const float* __restrict__ tc,
    const float* __restrict__ cls, const float* __restrict__ ccls,
    float* __restrict__ xm, float* __restrict__ xc)
{
    int idx = blockIdx.x * 256 + threadIdx.x;
    if (idx >= NROWS * EE) return;
    int e = idx % EE;
    int r = idx / EE;
    int b = r / NN, n = r % NN;
    if (n == 0) {
        xm[idx] = cls[e];
        xc[idx] = ccls[e];
    } else {
        size_t s = ((size_t)(b * NPATCH + n - 1)) * EE + e;
        xm[idx] = tm[s];
        xc[idx] = tc[s];
    }
}

// =============== merged LayerNorm for both streams (layer-0 norm1 only) ===============
__global__ __launch_bounds__(256) void ln2_kernel(
    const float* __restrict__ xm, const float* __restrict__ xc,
    unsigned short* __restrict__ y, const float* __restrict__ g,
    const float* __restrict__ bb)
{
    int row = blockIdx.x;
    int tid = threadIdx.x;
    const float* src;
    size_t orow;
    if (row < NROWS) { src = xm + (size_t)row * EE; orow = row; }
    else { src = xc + (size_t)(row - NROWS) * EE; orow = (size_t)(row - NROWS) + MPAD; }
    __shared__ float red[256];
    float v0 = src[tid], v1 = src[tid + 256], v2 = src[tid + 512];
    red[tid] = v0 + v1 + v2;
    __syncthreads();
    for (int s = 128; s > 0; s >>= 1) { if (tid < s) red[tid] += red[tid + s]; __syncthreads(); }
    float mu = red[0] * (1.f / 768.f);
    __syncthreads();
    float d0 = v0 - mu, d1 = v1 - mu, d2 = v2 - mu;
    red[tid] = d0 * d0 + d1 * d1 + d2 * d2;
    __syncthreads();
    for (int s = 128; s > 0; s >>= 1) { if (tid < s) red[tid] += red[tid + s]; __syncthreads(); }
    float rstd = rsqrtf(red[0] * (1.f / 768.f) + 1e-5f);
    unsigned short* yr = y + orow * EE;
    yr[tid]       = f2b(d0 * rstd * g[tid]       + bb[tid]);
    yr[tid + 256] = f2b(d1 * rstd * g[tid + 256] + bb[tid + 256]);
    yr[tid + 512] = f2b(d2 * rstd * g[tid + 512] + bb[tid + 512]);
}

// =============== mean-pool + LN (fp32), wave-parallel over tokens ===============
__global__ __launch_bounds__(256) void pool_ln_kernel(
    const float* __restrict__ xm, float* __restrict__ out,
    const float* __restrict__ g, const float* __restrict__ bb)
{
    int b = blockIdx.x;
    int tid = threadIdx.x;
    int w = tid >> 6, lane = tid & 63;
    __shared__ float part[4][768];
    float acc[12];
#pragma unroll
    for (int i = 0; i < 12; i++) acc[i] = 0.f;
    for (int n = w; n < NPATCH; n += 4) {
        const float* row = xm + ((size_t)(b * NN + 1 + n)) * EE;
#pragma unroll
        for (int i = 0; i < 12; i++) acc[i] += row[lane + i * 64];
    }
#pragma unroll
    for (int i = 0; i < 12; i++) part[w][lane + i * 64] = acc[i];
    __syncthreads();
    __shared__ float red[256];
    float p[3];
#pragma unroll
    for (int i = 0; i < 3; i++) {
        int e = tid + i * 256;
        p[i] = (part[0][e] + part[1][e] + part[2][e] + part[3][e]) * (1.f / 196.f);
    }
    red[tid] = p[0] + p[1] + p[2];
    __syncthreads();
    for (int s = 128; s > 0; s >>= 1) { if (tid < s) red[tid] += red[tid + s]; __syncthreads(); }
    float mu = red[0] * (1.f / 768.f);
    __syncthreads();
    float d0 = p[0] - mu, d1 = p[1] - mu, d2 = p[2] - mu;
    red[tid] = d0 * d0 + d1 * d1 + d2 * d2;
    __syncthreads();
    for (int s = 128; s > 0; s >>= 1) { if (tid < s) red[tid] += red[tid + s]; __syncthreads(); }
    float rstd = rsqrtf(red[0] * (1.f / 768.f) + 1e-5f);
    out[(size_t)b * EE + tid]       = d0 * rstd * g[tid]       + bb[tid];
    out[(size_t)b * EE + tid + 256] = d1 * rstd * g[tid + 256] + bb[tid + 256];
    out[(size_t)b * EE + tid + 512] = d2 * rstd * g[tid + 512] + bb[tid + 512];
}

// =========================================================================
extern "C" void kernel_launch(void* const* d_in, const int* in_sizes, int n_in,
                              void* d_out, int out_size, void* d_ws, size_t ws_size,
                              hipStream_t stream)
{
    const float* x        = (const float*)d_in[0];
    const float* rpb      = (const float*)d_in[1];
    const float* patch_w  = (const float*)d_in[2];
    const float* patch_b  = (const float*)d_in[3];
    const float* cpatch_w = (const float*)d_in[4];
    const float* cpatch_b = (const float*)d_in[5];
    const float* cls_tok  = (const float*)d_in[6];
    const float* ccls_tok = (const float*)d_in[7];
    const float* norm1_g  = (const float*)d_in[8];
    const float* norm1_b  = (const float*)d_in[9];
    const float* qkv_w    = (const float*)d_in[10];
    const float* q_bias   = (const float*)d_in[11];
    const float* v_bias   = (const float*)d_in[12];
    const float* cq_bias  = (const float*)d_in[13];
    const float* cv_bias  = (const float*)d_in[14];
    const float* proj_w   = (const float*)d_in[15];
    const float* proj_b   = (const float*)d_in[16];
    const float* cproj_w  = (const float*)d_in[17];
    const float* cproj_b  = (const float*)d_in[18];
    const float* gamma1   = (const float*)d_in[19];
    const float* gamma2   = (const float*)d_in[20];
    const float* norm2_g  = (const float*)d_in[21];
    const float* norm2_b  = (const float*)d_in[22];
    const float* fc1_w    = (const float*)d_in[23];
    const float* fc1_b    = (const float*)d_in[24];
    const float* fc2_w    = (const float*)d_in[25];
    const float* fc2_b    = (const float*)d_in[26];
    const float* fcn_g    = (const float*)d_in[27];
    const float* fcn_b    = (const float*)d_in[28];
    const float* head_w   = (const float*)d_in[29];
    const float* head_b   = (const float*)d_in[30];
    float* out = (float*)d_out;

    // ---- workspace layout (~350 MB; harness fill indicates ~432 MiB available) ----
    char* base = (char*)d_ws;
    size_t off = 0;
    auto alloc = [&](size_t bytes) {
        void* p = base + off;
        off = (off + bytes + 255) & ~(size_t)255;
        return p;
    };
    unsigned short* wbuf  = (unsigned short*)alloc((size_t)LL * W_TOTAL * 2);  // 184 MB
    unsigned short* pw_m  = (unsigned short*)alloc((size_t)PW_ELEMS * 2);
    unsigned short* pw_c  = (unsigned short*)alloc((size_t)PW_ELEMS * 2);
    float* xm   = (float*)alloc((size_t)MPAD * EE * 4);
    float* xc   = (float*)alloc((size_t)MPAD * EE * 4);
    unsigned short* xn2 = (unsigned short*)alloc((size_t)2 * MPAD * EE * 2);
    float* qkv  = (float*)alloc((size_t)MPAD * 3 * EE * 4);
    float* cqkv = (float*)alloc((size_t)MPAD * 3 * EE * 4);
    unsigned short* hbuf = (unsigned short*)alloc((size_t)2 * MPAD * MLPD * 2);
    unsigned short* Aq  = (unsigned short*)alloc((size_t)NBH * NP256 * 128 * 2);
    unsigned short* Bk  = (unsigned short*)alloc((size_t)NBH * NP256 * 128 * 2);
    unsigned short* vT  = (unsigned short*)alloc((size_t)NBH * 64 * NP224 * 2);
    unsigned short* cvT = (unsigned short*)alloc((size_t)NBH * 64 * NP224 * 2);
    float* rsum = (float*)alloc((size_t)NBH * NP256 * 4);
    float* csum = (float*)alloc((size_t)NBH * NP256 * 4);
    unsigned short* ctx2 = (unsigned short*)alloc((size_t)2 * MPAD * EE * 2);
    unsigned short* colb = (unsigned short*)alloc((size_t)MPAD * EE * 2);
    float* bqc    = (float*)alloc((size_t)LL * 2 * 2304 * 4);
    float* pooled = (float*)alloc((size_t)BB * EE * 4);
    // split-K partial buffer: up to 2 halves x 6 splits x [MPAD][EE] fp32 (61.3 MB)
    float* pbuf = (float*)alloc((size_t)2 * 6 * MPAD * EE * 4);
    // aliases
    float* tm = qkv;
    float* tc = cqkv;
    unsigned short* ctxm = ctx2;
    unsigned short* ctxc = ctx2 + (size_t)MPAD * EE;

    dim3 t256(256);
    dim3 gridRedE(MPAD * EE / 1024, 2);
    dim3 gridRedLN(MPAD, 2);

    // ---- one-shot weight + bias conversion (all layers + patch weights) ----
    cvt_all_kernel<<<dim3(4096), t256, 0, stream>>>(
        qkv_w, proj_w, cproj_w, fc1_w, fc2_w, patch_w, cpatch_w, wbuf, pw_m, pw_c);
    qkvbias_all_kernel<<<dim3(9, LL), t256, 0, stream>>>(
        q_bias, v_bias, cq_bias, cv_bias, bqc);

    // ---- patch embed (split-K S=3) ----
    im2col_kernel<<<dim3((PROWS * EE + 255) / 256), t256, 0, stream>>>(x, colb);
    mfma_gemm2_sk<<<dim3(EE / 128, 2 * HTILES, 3), t256, 0, stream>>>(
        colb, colb, pw_m, pw_c, EE, 256, EE, 3, pbuf);
    sk_reduce_kernel<<<gridRedE, t256, 0, stream>>>(
        pbuf, 3, EE, patch_b, cpatch_b, tm, tc);
    assemble_kernel<<<dim3((NROWS * EE + 255) / 256), t256, 0, stream>>>(
        tm, tc, cls_tok, ccls_tok, xm, xc);
    // layer-0 norm1
    ln2_kernel<<<dim3(2 * NROWS), t256, 0, stream>>>(xm, xc, xn2, norm1_g, norm1_b);

    dim3 gridQKV(3 * EE / 128, 2 * HTILES);
    dim3 gridMLP(MLPD / 128, 2 * HTILES);
    dim3 gridPre(4, NBH);
    dim3 gridAttn(4, NBH);
    const unsigned short* xn2c = xn2 + (size_t)MPAD * EE;
    const unsigned short* hbufc = hbuf + (size_t)MPAD * MLPD;

    for (int l = 0; l < LL; l++) {
        const unsigned short* wl = wbuf + (size_t)l * W_TOTAL;
        const float* biasq = bqc + (size_t)l * 4608;
        const float* biasc = biasq + 2304;

        // qkv dual GEMM (xn2 produced by previous layer's fc2 reduce / layer-0 ln2)
        mfma_gemm2<<<gridQKV, t256, 0, stream>>>(
            xn2, xn2c, wl + W_QKV, wl + W_QKV, biasq, biasc, EE, 3 * EE,
            MODE_F32, MODE_ELU1F, nullptr, nullptr, nullptr, qkv, cqkv, nullptr, nullptr);

        // attention: pre + fully fused wass/softmax/PV
        pre_kernel<<<gridPre, t256, 0, stream>>>(qkv, cqkv, Aq, Bk, rsum, csum, vT, cvT);
        attn_fused<<<gridAttn, t256, 0, stream>>>(Aq, Bk, rsum, csum, rpb, vT, cvT, ctxm, ctxc);

        // proj dual (split-K S=3) + reduce fused with residual AND norm2 LN
        mfma_gemm2_sk<<<dim3(EE / 128, 2 * HTILES, 3), t256, 0, stream>>>(
            ctxm, ctxc, wl + W_PROJ, wl + W_CPROJ, EE, 256, EE, 3, pbuf);
        sk_reduce_ln<<<gridRedLN, t256, 0, stream>>>(
            pbuf, 3, proj_b + l * EE, cproj_b + l * EE,
            gamma1 + l * EE, xm, xc, xm, xc,
            norm2_g + l * EE, norm2_b + l * EE, xn2);

        // MLP dual
        mfma_gemm2<<<gridMLP, t256, 0, stream>>>(
            xn2, xn2c, wl + W_FC1, wl + W_FC1, fc1_b + l * MLPD, fc1_b + l * MLPD,
            EE, MLPD, MODE_GELUB, MODE_GELUB, nullptr, nullptr, nullptr,
            nullptr, nullptr, hbuf, hbuf + (size_t)MPAD * MLPD);
        // fc2 dual (split-K S=6: 936 wg = 3.7 blk/CU) + reduce fused with residual + next norm1
        mfma_gemm2_sk<<<dim3(EE / 128, 2 * HTILES, 6), t256, 0, stream>>>(
            hbuf, hbufc, wl + W_FC2, wl + W_FC2, MLPD, 512, EE, 6, pbuf);
        if (l + 1 < LL) {
            sk_reduce_ln<<<gridRedLN, t256, 0, stream>>>(
                pbuf, 6, fc2_b + l * EE, fc2_b + l * EE,
                gamma2 + l * EE, xm, xc, xm, xc,
                norm1_g + (l + 1) * EE, norm1_b + (l + 1) * EE, xn2);
        } else {
            sk_reduce_ln<<<gridRedLN, t256, 0, stream>>>(
                pbuf, 6, fc2_b + l * EE, fc2_b + l * EE,
                gamma2 + l * EE, xm, xc, xm, xc,
                nullptr, nullptr, nullptr);
        }
    }

    // ---- head ----
    pool_ln_kernel<<<dim3(BB), t256, 0, stream>>>(xm, pooled, fcn_g, fcn_b);
    head_kernel<<<dim3((NCLS + 3) / 4, BB), t256, 0, stream>>>(pooled, head_w, head_b, out);
}